// Round 11
// baseline (152.784 us; speedup 1.0000x reference)
//
#include <hip/hip_runtime.h>
#include <hip/hip_bf16.h>

#define CH   1024
#define BSZ  16
#define LSEQ 4096
#define NST  16

typedef __attribute__((ext_vector_type(8))) short short8;
typedef __attribute__((ext_vector_type(4))) float f32x4;

__device__ __forceinline__ unsigned int pkrn(float a, float b) {
    __hip_bfloat162 h = __float22bfloat162_rn(make_float2(a, b));
    unsigned int u;
    __builtin_memcpy(&u, &h, 4);
    return u;
}
__device__ __forceinline__ float rfl(float x) {
    return __int_as_float(__builtin_amdgcn_readfirstlane(__float_as_int(x)));
}
// row_shr:d within 16-lane rows, OOB lanes read 0
#define DSHR(x, d) __int_as_float(__builtin_amdgcn_update_dpp(0, __float_as_int(x), 0x110 + (d), 0xf, 0xf, true))
// masked broadcast (rows not in RM get 0)
#define DBC(x, ctrl, rm) __int_as_float(__builtin_amdgcn_update_dpp(0, __float_as_int(x), (ctrl), (rm), 0xf, true))

#define XT0_OFF 0
#define XT1_OFF 8192
#define S_OFF   16384
#define SIN_OFF 24704
#define SMEM_SZ 28800

// barrier that drains ONLY lgkmcnt (LDS) — y-stores/x-loads stay in flight
__device__ __forceinline__ void barrier_fast() {
    asm volatile("s_waitcnt lgkmcnt(0)\n\ts_barrier" ::: "memory");
}

__global__ __launch_bounds__(256, 5) void conv_k(const float* __restrict__ x,
                                                 const float* __restrict__ A,
                                                 const float* __restrict__ log_dt,
                                                 const float* __restrict__ E,
                                                 float* __restrict__ y) {
    __shared__ __align__(16) char smem[SMEM_SZ];
    const int tid  = threadIdx.x;
    const int w    = tid >> 6, lane = tid & 63;
    const int g    = lane >> 4, l15 = lane & 15;
    const int bid  = blockIdx.x;
    const int c    = bid >> 1;
    const int half = bid & 1;                 // batches 8*half .. 8*half+7

    const size_t cstride = (size_t)CH * LSEQ;
    const float* xr = x + ((size_t)(8 * half) * CH + c) * (size_t)LSEQ;
    float*       yb = y + ((size_t)(8 * half) * CH + c) * (size_t)LSEQ;

    // ---- staging addresses ----
    int stb[2];
#pragma unroll
    for (int it = 0; it < 2; ++it) {
        int slot = it * 256 + tid;
        int m = slot >> 3, js = slot & 7;
        stb[it] = (m * 128 + js * 16) ^ ((m & 7) << 4);
    }
    float4 pend[4];
    auto ldraw = [&](const float* xp) {
#pragma unroll
        for (int it = 0; it < 2; ++it) {
            int slot = it * 256 + tid;
            pend[2 * it]     = *(const float4*)(xp + slot * 8);
            pend[2 * it + 1] = *(const float4*)(xp + slot * 8 + 4);
        }
    };
    auto stage = [&](int xoff) {
#pragma unroll
        for (int it = 0; it < 2; ++it) {
            uint4 pk;
            pk.x = pkrn(pend[2 * it].x,     pend[2 * it].y);
            pk.y = pkrn(pend[2 * it].z,     pend[2 * it].w);
            pk.z = pkrn(pend[2 * it + 1].x, pend[2 * it + 1].y);
            pk.w = pkrn(pend[2 * it + 1].z, pend[2 * it + 1].w);
            *(uint4*)(smem + xoff + stb[it]) = pk;
        }
    };

    ldraw(xr);                                 // row 0: issue ASAP, hides under prologue

    // ---- fused setup: lambda-power tables in LDS (S/SIN regions, freed before main loop) ----
    float* PR = (float*)(smem + S_OFF);        // [16][65]
    float* PI = PR + NST * 65;                 // [16][65]
    float* EH = (float*)(smem + SIN_OFF);      // [16]
    float* KL = EH + NST;                      // [64]
    {
        int n = tid & 15;
        int idx0 = c * NST + n;
        float a0 = A[2 * idx0], a1 = A[2 * idx0 + 1];
        float sp = (a0 > 20.f) ? a0 : log1pf(expf(a0));   // softplus
        float dtv = expf(log_dt[idx0]);
        float dar = -dtv * sp, dai = dtv * a1;
        if (tid < NST) EH[tid] = E[idx0] * dtv;
        for (int l = tid >> 4; l < 65; l += 16) {
            float mg = expf(dar * (float)l);
            float s, cs;
            sincosf(dai * (float)l, &s, &cs);
            PR[n * 65 + l] = mg * cs;
            PI[n * 65 + l] = mg * s;
        }
    }
    __syncthreads();
    if (tid < 64) {
        float kl = 0.f;
#pragma unroll
        for (int nn = 0; nn < NST; ++nn) kl += EH[nn] * PR[nn * 65 + tid];
        KL[tid] = kl;
    }
    __syncthreads();

    // ---- assemble MFMA fragments from LDS tables ----
    short8 wa[2], pa[3];
    {
        int p = 16 * (w >> 1) + l15;
        const float* tb = ((p & 1) ? PI : PR) + (p >> 1) * 65;
#pragma unroll
        for (int kt = 0; kt < 2; ++kt) {
            union { short8 v; unsigned int d[4]; } u;
#pragma unroll
            for (int e2 = 0; e2 < 4; ++e2) {
                int j = kt * 32 + 8 * g + 2 * e2;
                u.d[e2] = pkrn(tb[63 - j], tb[62 - j]);
            }
            wa[kt] = u.v;
        }
        int i = 16 * w + l15;
#pragma unroll
        for (int kt = 0; kt < 2; ++kt) {
            union { short8 v; unsigned int d[4]; } u;
#pragma unroll
            for (int e2 = 0; e2 < 4; ++e2) {
                int k0 = kt * 32 + 8 * g + 2 * e2;
                float v0 = (k0 <= i)     ? KL[i - k0]     : 0.f;
                float v1 = (k0 + 1 <= i) ? KL[i - k0 - 1] : 0.f;
                u.d[e2] = pkrn(v0, v1);
            }
            pa[kt] = u.v;
        }
        {
            union { short8 v; unsigned int d[4]; } u;
#pragma unroll
            for (int e2 = 0; e2 < 4; ++e2) {
                int n3 = 4 * g + e2;
                float re = EH[n3] * PR[n3 * 65 + i + 1];
                float im = -EH[n3] * PI[n3 * 65 + i + 1];
                u.d[e2] = pkrn(re, im);
            }
            pa[2] = u.v;
        }
    }

    // ---- q powers (wave-uniform -> SGPR) + per-lane carry factors f,h ----
    float q1r[4], q1i[4], q2r[4], q2i[4], q4r[4], q4i[4], q8r[4], q8i[4];
    float fr[4], fi[4], hr[4], hi[4];
#pragma unroll
    for (int k = 0; k < 4; ++k) {
        int nn = 4 * w + k;
        float ar = PR[nn * 65 + 64], ai = PI[nn * 65 + 64];
        float b2r = fmaf(ar, ar, -(ai * ai)), b2i = 2.f * ar * ai;
        float b4r = fmaf(b2r, b2r, -(b2i * b2i)), b4i = 2.f * b2r * b2i;
        float b8r = fmaf(b4r, b4r, -(b4i * b4i)), b8i = 2.f * b4r * b4i;
        float b16r = fmaf(b8r, b8r, -(b8i * b8i)), b16i = 2.f * b8r * b8i;
        q1r[k] = rfl(ar);  q1i[k] = rfl(ai);
        q2r[k] = rfl(b2r); q2i[k] = rfl(b2i);
        q4r[k] = rfl(b4r); q4i[k] = rfl(b4i);
        q8r[k] = rfl(b8r); q8i[k] = rfl(b8i);
        float cr = ar, ci = ai;
        {
            float tr = fmaf(cr, ar, -(ci * ai)), ti = fmaf(cr, ai, ci * ar);
            cr = (l15 & 1) ? tr : cr; ci = (l15 & 1) ? ti : ci;
        }
        {
            float tr = fmaf(cr, b2r, -(ci * b2i)), ti = fmaf(cr, b2i, ci * b2r);
            cr = (l15 & 2) ? tr : cr; ci = (l15 & 2) ? ti : ci;
        }
        {
            float tr = fmaf(cr, b4r, -(ci * b4i)), ti = fmaf(cr, b4i, ci * b4r);
            cr = (l15 & 4) ? tr : cr; ci = (l15 & 4) ? ti : ci;
        }
        {
            float tr = fmaf(cr, b8r, -(ci * b8i)), ti = fmaf(cr, b8i, ci * b8r);
            cr = (l15 & 8) ? tr : cr; ci = (l15 & 8) ? ti : ci;
        }
        fr[k] = cr; fi[k] = ci;
        float tr = fmaf(cr, b16r, -(ci * b16i)), ti = fmaf(cr, b16i, ci * b16r);
        bool r3 = (lane >= 48);
        hr[k] = r3 ? tr : cr; hi[k] = r3 ? ti : ci;
    }

    // ---- precomputed main-loop addresses ----
    int xfo[4][2], sino[4];
#pragma unroll
    for (int nt = 0; nt < 4; ++nt) {
#pragma unroll
        for (int kt = 0; kt < 2; ++kt)
            xfo[nt][kt] = ((l15 * 128 + kt * 64 + g * 16) ^ ((l15 & 7) << 4)) + nt * 2048;
        sino[nt] = ((l15 * 64 + g * 16) ^ ((l15 & 3) << 4)) + nt * 1024;
    }
    const int ntb  = (w & 1) << 1;
    const int swb  = ((16 * (w >> 1) + 4 * g) * 65 + l15 + 16 * ntb) * 4;
    const int srb  = (8 * w * 65 + lane) * 4;
    const int sinw = (lane * 64 + 16 * w) ^ ((lane & 3) << 4);

    auto scan = [&]() {
        float sr[4], si[4];
#pragma unroll
        for (int k = 0; k < 4; ++k) {
            sr[k] = *(const float*)(smem + S_OFF + srb + k * 520);
            si[k] = *(const float*)(smem + S_OFF + srb + k * 520 + 260);
        }
#pragma unroll
        for (int k = 0; k < 4; ++k) {
            { float ur = DSHR(sr[k], 1), ui = DSHR(si[k], 1);
              sr[k] = fmaf(q1r[k], ur, fmaf(-q1i[k], ui, sr[k]));
              si[k] = fmaf(q1r[k], ui, fmaf(q1i[k], ur, si[k])); }
            { float ur = DSHR(sr[k], 2), ui = DSHR(si[k], 2);
              sr[k] = fmaf(q2r[k], ur, fmaf(-q2i[k], ui, sr[k]));
              si[k] = fmaf(q2r[k], ui, fmaf(q2i[k], ur, si[k])); }
            { float ur = DSHR(sr[k], 4), ui = DSHR(si[k], 4);
              sr[k] = fmaf(q4r[k], ur, fmaf(-q4i[k], ui, sr[k]));
              si[k] = fmaf(q4r[k], ui, fmaf(q4i[k], ur, si[k])); }
            { float ur = DSHR(sr[k], 8), ui = DSHR(si[k], 8);
              sr[k] = fmaf(q8r[k], ur, fmaf(-q8i[k], ui, sr[k]));
              si[k] = fmaf(q8r[k], ui, fmaf(q8i[k], ur, si[k])); }
            { float ur = DBC(sr[k], 0x142, 0xa), ui = DBC(si[k], 0x142, 0xa);
              sr[k] = fmaf(fr[k], ur, fmaf(-fi[k], ui, sr[k]));
              si[k] = fmaf(fr[k], ui, fmaf(fi[k], ur, si[k])); }
            { float ur = DBC(sr[k], 0x143, 0xc), ui = DBC(si[k], 0x143, 0xc);
              sr[k] = fmaf(hr[k], ur, fmaf(-hi[k], ui, sr[k]));
              si[k] = fmaf(hr[k], ui, fmaf(hi[k], ur, si[k])); }
        }
        unsigned int dw[4];
#pragma unroll
        for (int k = 0; k < 4; ++k) {
            float ar = __shfl_up(sr[k], 1);
            float ai = __shfl_up(si[k], 1);
            ar = (lane > 0) ? ar : 0.f;
            ai = (lane > 0) ? ai : 0.f;
            dw[k] = pkrn(ar, ai);
        }
        *(uint4*)(smem + SIN_OFF + sinw) = make_uint4(dw[0], dw[1], dw[2], dw[3]);
    };

    // ---- one row-phase.  xf loaded in 2 halves (16 VGPR live, not 32);
    //      next-row loads issued after xf dies; stage after scan. ----
    auto row = [&](int xc, int xn, float* yr, const float* xpre, bool do_stage) {
        f32x4 acc[4];
        f32x4 s0 = {0.f, 0.f, 0.f, 0.f}, s1 = {0.f, 0.f, 0.f, 0.f};
        const f32x4 z = {0.f, 0.f, 0.f, 0.f};
        short8 xfA[2][2];
        if ((w & 1) == 0) {
            // half 1: nt 0,1 (this wave's gemm1 pair)
#pragma unroll
            for (int kt = 0; kt < 2; ++kt) {
                xfA[0][kt] = *(const short8*)(smem + xc + xfo[0][kt]);
                xfA[1][kt] = *(const short8*)(smem + xc + xfo[1][kt]);
            }
#pragma unroll
            for (int kt = 0; kt < 2; ++kt) {
                s0 = __builtin_amdgcn_mfma_f32_16x16x32_bf16(wa[kt], xfA[0][kt], s0, 0, 0, 0);
                s1 = __builtin_amdgcn_mfma_f32_16x16x32_bf16(wa[kt], xfA[1][kt], s1, 0, 0, 0);
            }
            acc[0] = __builtin_amdgcn_mfma_f32_16x16x32_bf16(pa[0], xfA[0][0], z, 0, 0, 0);
            acc[1] = __builtin_amdgcn_mfma_f32_16x16x32_bf16(pa[0], xfA[1][0], z, 0, 0, 0);
            if (w >= 2) {
                acc[0] = __builtin_amdgcn_mfma_f32_16x16x32_bf16(pa[1], xfA[0][1], acc[0], 0, 0, 0);
                acc[1] = __builtin_amdgcn_mfma_f32_16x16x32_bf16(pa[1], xfA[1][1], acc[1], 0, 0, 0);
            }
            // half 2: nt 2,3 (reuse regs)
#pragma unroll
            for (int kt = 0; kt < 2; ++kt) {
                xfA[0][kt] = *(const short8*)(smem + xc + xfo[2][kt]);
                xfA[1][kt] = *(const short8*)(smem + xc + xfo[3][kt]);
            }
            acc[2] = __builtin_amdgcn_mfma_f32_16x16x32_bf16(pa[0], xfA[0][0], z, 0, 0, 0);
            acc[3] = __builtin_amdgcn_mfma_f32_16x16x32_bf16(pa[0], xfA[1][0], z, 0, 0, 0);
            if (w >= 2) {
                acc[2] = __builtin_amdgcn_mfma_f32_16x16x32_bf16(pa[1], xfA[0][1], acc[2], 0, 0, 0);
                acc[3] = __builtin_amdgcn_mfma_f32_16x16x32_bf16(pa[1], xfA[1][1], acc[3], 0, 0, 0);
            }
        } else {
            // half 1: nt 2,3 (this wave's gemm1 pair)
#pragma unroll
            for (int kt = 0; kt < 2; ++kt) {
                xfA[0][kt] = *(const short8*)(smem + xc + xfo[2][kt]);
                xfA[1][kt] = *(const short8*)(smem + xc + xfo[3][kt]);
            }
#pragma unroll
            for (int kt = 0; kt < 2; ++kt) {
                s0 = __builtin_amdgcn_mfma_f32_16x16x32_bf16(wa[kt], xfA[0][kt], s0, 0, 0, 0);
                s1 = __builtin_amdgcn_mfma_f32_16x16x32_bf16(wa[kt], xfA[1][kt], s1, 0, 0, 0);
            }
            acc[2] = __builtin_amdgcn_mfma_f32_16x16x32_bf16(pa[0], xfA[0][0], z, 0, 0, 0);
            acc[3] = __builtin_amdgcn_mfma_f32_16x16x32_bf16(pa[0], xfA[1][0], z, 0, 0, 0);
            if (w >= 2) {
                acc[2] = __builtin_amdgcn_mfma_f32_16x16x32_bf16(pa[1], xfA[0][1], acc[2], 0, 0, 0);
                acc[3] = __builtin_amdgcn_mfma_f32_16x16x32_bf16(pa[1], xfA[1][1], acc[3], 0, 0, 0);
            }
            // half 2: nt 0,1
#pragma unroll
            for (int kt = 0; kt < 2; ++kt) {
                xfA[0][kt] = *(const short8*)(smem + xc + xfo[0][kt]);
                xfA[1][kt] = *(const short8*)(smem + xc + xfo[1][kt]);
            }
            acc[0] = __builtin_amdgcn_mfma_f32_16x16x32_bf16(pa[0], xfA[0][0], z, 0, 0, 0);
            acc[1] = __builtin_amdgcn_mfma_f32_16x16x32_bf16(pa[0], xfA[1][0], z, 0, 0, 0);
            if (w >= 2) {
                acc[0] = __builtin_amdgcn_mfma_f32_16x16x32_bf16(pa[1], xfA[0][1], acc[0], 0, 0, 0);
                acc[1] = __builtin_amdgcn_mfma_f32_16x16x32_bf16(pa[1], xfA[1][1], acc[1], 0, 0, 0);
            }
        }
        // S writes (gemm1 result)
#pragma unroll
        for (int r = 0; r < 4; ++r) {
            *(float*)(smem + S_OFF + swb + r * 260)      = s0[r];
            *(float*)(smem + S_OFF + swb + r * 260 + 64) = s1[r];
        }
        asm volatile("" :: "v"(acc[0]), "v"(acc[1]), "v"(acc[2]), "v"(acc[3]));
        if (xpre) ldraw(xpre);                 // next-row loads: xf dead, regs free
        barrier_fast();
        scan();
        if (do_stage) stage(xn);               // vmcnt wait covered by scan
        barrier_fast();
#pragma unroll
        for (int nt = 0; nt < 4; ++nt) {
            short8 sf = *(const short8*)(smem + SIN_OFF + sino[nt]);
            acc[nt] = __builtin_amdgcn_mfma_f32_16x16x32_bf16(pa[2], sf, acc[nt], 0, 0, 0);
        }
#pragma unroll
        for (int nt = 0; nt < 4; ++nt) {
            int m = l15 + 16 * nt;
            float4 v = make_float4(acc[nt][0], acc[nt][1], acc[nt][2], acc[nt][3]);
            *(float4*)(yr + m * 64 + 16 * w + 4 * g) = v;
        }
    };

    // ---- prologue staging (tables consumed; safe to overwrite after barrier) ----
    stage(XT0_OFF);
    __syncthreads();

    int cur = XT0_OFF, nxt = XT1_OFF;
#pragma unroll 1
    for (int bb = 0; bb < 8; ++bb) {
        row(cur, nxt, yb + (size_t)bb * cstride,
            (bb < 7) ? (xr + (size_t)(bb + 1) * cstride) : nullptr, bb < 7);
        int t = cur; cur = nxt; nxt = t;
    }
}

extern "C" void kernel_launch(void* const* d_in, const int* in_sizes, int n_in,
                              void* d_out, int out_size, void* d_ws, size_t ws_size,
                              hipStream_t stream) {
    const float* x      = (const float*)d_in[0];
    const float* A      = (const float*)d_in[1];
    const float* log_dt = (const float*)d_in[4];
    const float* E      = (const float*)d_in[5];
    float* out = (float*)d_out;
    (void)d_ws; (void)ws_size;

    conv_k<<<2 * CH, 256, 0, stream>>>(x, A, log_dt, E, out);
}

// Round 12
// 110.777 us; speedup vs baseline: 1.3792x; 1.3792x over previous
//
#include <hip/hip_runtime.h>
#include <hip/hip_bf16.h>

#define CH   1024
#define LSEQ 4096
#define NST  16

typedef __attribute__((ext_vector_type(8))) short short8;
typedef __attribute__((ext_vector_type(4))) float f32x4;

__device__ __forceinline__ unsigned int pkrn(float a, float b) {
    __hip_bfloat162 h = __float22bfloat162_rn(make_float2(a, b));
    unsigned int u;
    __builtin_memcpy(&u, &h, 4);
    return u;
}
// row_shr:d within 16-lane rows, OOB lanes read 0
#define DSHR(x, d) __int_as_float(__builtin_amdgcn_update_dpp(0, __float_as_int(x), 0x110 + (d), 0xf, 0xf, true))
// broadcast lane 15 of own 16-lane row: lane = (lane & 0x10) | 0xF  (BitMode and=0x10, or=0xF)
__device__ __forceinline__ float swz15(float x) {
    return __int_as_float(__builtin_amdgcn_ds_swizzle(__float_as_int(x), 0x1F0));
}

#define XT0_OFF  0
#define XT1_OFF  8192
#define SIN0_OFF 16384
#define SIN1_OFF 20480
#define TBL_OFF  16384      // PR/PI tables (prologue only, overlap SIN buffers)
#define EH_OFF   24704
#define SMEM_SZ  25024

// barrier that drains ONLY lgkmcnt (LDS) — y-stores/x-loads stay in flight
__device__ __forceinline__ void barrier_fast() {
    asm volatile("s_waitcnt lgkmcnt(0)\n\ts_barrier" ::: "memory");
}

__global__ __launch_bounds__(256, 4) void conv_k(const float* __restrict__ x,
                                                 const float* __restrict__ A,
                                                 const float* __restrict__ log_dt,
                                                 const float* __restrict__ E,
                                                 float* __restrict__ y) {
    __shared__ __align__(16) char smem[SMEM_SZ];
    const int tid  = threadIdx.x;
    const int w    = tid >> 6, lane = tid & 63;
    const int g    = lane >> 4, l15 = lane & 15;
    const int a    = w >> 1, s = w & 1;
    const int bid  = blockIdx.x;
    const int c    = bid >> 1;
    const int half = bid & 1;                 // batches 8*half .. 8*half+7

    const size_t cstride = (size_t)CH * LSEQ;
    const float* xr = x + ((size_t)(8 * half) * CH + c) * (size_t)LSEQ;
    float*       yb = y + ((size_t)(8 * half) * CH + c) * (size_t)LSEQ;

    // ---- staging addresses ----
    int stb[2];
#pragma unroll
    for (int it = 0; it < 2; ++it) {
        int slot = it * 256 + tid;
        int m = slot >> 3, js = slot & 7;
        stb[it] = (m * 128 + js * 16) ^ ((m & 7) << 4);
    }
    float4 pend[4];
    auto ldraw = [&](const float* xp) {
#pragma unroll
        for (int it = 0; it < 2; ++it) {
            int slot = it * 256 + tid;
            pend[2 * it]     = *(const float4*)(xp + slot * 8);
            pend[2 * it + 1] = *(const float4*)(xp + slot * 8 + 4);
        }
    };
    auto stage = [&](int xoff) {
#pragma unroll
        for (int it = 0; it < 2; ++it) {
            uint4 pk;
            pk.x = pkrn(pend[2 * it].x,     pend[2 * it].y);
            pk.y = pkrn(pend[2 * it].z,     pend[2 * it].w);
            pk.z = pkrn(pend[2 * it + 1].x, pend[2 * it + 1].y);
            pk.w = pkrn(pend[2 * it + 1].z, pend[2 * it + 1].w);
            *(uint4*)(smem + xoff + stb[it]) = pk;
        }
    };

    ldraw(xr);                                 // row 0 loads, issue ASAP

    // ---- fused setup: lambda-power tables in LDS ----
    float* PR = (float*)(smem + TBL_OFF);      // [16][65]
    float* PI = PR + NST * 65;                 // [16][65]
    float* EH = (float*)(smem + EH_OFF);       // [16]
    float* KL = EH + NST;                      // [64]
    {
        int n = tid & 15;
        int idx0 = c * NST + n;
        float a0 = A[2 * idx0], a1 = A[2 * idx0 + 1];
        float sp = (a0 > 20.f) ? a0 : log1pf(expf(a0));   // softplus
        float dtv = expf(log_dt[idx0]);
        float dar = -dtv * sp, dai = dtv * a1;
        if (tid < NST) EH[tid] = E[idx0] * dtv;
        for (int l = tid >> 4; l < 65; l += 16) {
            float mg = expf(dar * (float)l);
            float sn, cs;
            sincosf(dai * (float)l, &sn, &cs);
            PR[n * 65 + l] = mg * cs;
            PI[n * 65 + l] = mg * sn;
        }
    }
    __syncthreads();
    if (tid < 64) {
        float kl = 0.f;
#pragma unroll
        for (int nn = 0; nn < NST; ++nn) kl += EH[nn] * PR[nn * 65 + tid];
        KL[tid] = kl;
    }
    __syncthreads();

    // ---- assemble MFMA fragments from LDS tables ----
    short8 wa[2], pa[3];
    {
        int p = 16 * a + l15;
        const float* tb = ((p & 1) ? PI : PR) + (p >> 1) * 65;
#pragma unroll
        for (int kt = 0; kt < 2; ++kt) {
            union { short8 v; unsigned int d[4]; } u;
#pragma unroll
            for (int e2 = 0; e2 < 4; ++e2) {
                int j = kt * 32 + 8 * g + 2 * e2;
                u.d[e2] = pkrn(tb[63 - j], tb[62 - j]);
            }
            wa[kt] = u.v;
        }
        int i = 16 * w + l15;
#pragma unroll
        for (int kt = 0; kt < 2; ++kt) {
            union { short8 v; unsigned int d[4]; } u;
#pragma unroll
            for (int e2 = 0; e2 < 4; ++e2) {
                int k0 = kt * 32 + 8 * g + 2 * e2;
                float v0 = (k0 <= i)     ? KL[i - k0]     : 0.f;
                float v1 = (k0 + 1 <= i) ? KL[i - k0 - 1] : 0.f;
                u.d[e2] = pkrn(v0, v1);
            }
            pa[kt] = u.v;
        }
        {
            union { short8 v; unsigned int d[4]; } u;
#pragma unroll
            for (int e2 = 0; e2 < 4; ++e2) {
                int n3 = 4 * g + e2;
                float re = EH[n3] * PR[n3 * 65 + i + 1];
                float im = -EH[n3] * PI[n3 * 65 + i + 1];
                u.d[e2] = pkrn(re, im);
            }
            pa[2] = u.v;
        }
    }

    // ---- per-lane scan constants: state n = 8a+2g+s, q = lam^64 (per lane!) ----
    float q1r, q1i, q2r, q2i, q4r, q4i, q8r, q8i, fr_, fi_;
    {
        int nq = 8 * a + 2 * g + s;
        q1r = PR[nq * 65 + 64];
        q1i = PI[nq * 65 + 64];
        q2r = fmaf(q1r, q1r, -(q1i * q1i)); q2i = 2.f * q1r * q1i;
        q4r = fmaf(q2r, q2r, -(q2i * q2i)); q4i = 2.f * q2r * q2i;
        q8r = fmaf(q4r, q4r, -(q4i * q4i)); q8i = 2.f * q4r * q4i;
        // f = q^(l15+1)
        float cr = q1r, ci = q1i;
        { float tr = fmaf(cr, q1r, -(ci * q1i)), ti = fmaf(cr, q1i, ci * q1r);
          cr = (l15 & 1) ? tr : cr; ci = (l15 & 1) ? ti : ci; }
        { float tr = fmaf(cr, q2r, -(ci * q2i)), ti = fmaf(cr, q2i, ci * q2r);
          cr = (l15 & 2) ? tr : cr; ci = (l15 & 2) ? ti : ci; }
        { float tr = fmaf(cr, q4r, -(ci * q4i)), ti = fmaf(cr, q4i, ci * q4r);
          cr = (l15 & 4) ? tr : cr; ci = (l15 & 4) ? ti : ci; }
        { float tr = fmaf(cr, q8r, -(ci * q8i)), ti = fmaf(cr, q8i, ci * q8r);
          cr = (l15 & 8) ? tr : cr; ci = (l15 & 8) ? ti : ci; }
        fr_ = cr; fi_ = ci;
    }

    // ---- precomputed main-loop addresses ----
    int xfo[4][2], sino[4];
#pragma unroll
    for (int nt = 0; nt < 4; ++nt) {
#pragma unroll
        for (int kt = 0; kt < 2; ++kt)
            xfo[nt][kt] = ((l15 * 128 + kt * 64 + g * 16) ^ ((l15 & 7) << 4)) + nt * 2048;
        sino[nt] = ((l15 * 64 + g * 16) ^ ((l15 & 3) << 4)) + nt * 1024;
    }
    const int sinwb = (l15 * 64 + 8 * g + 32 * a + 4 * s) ^ ((l15 & 3) << 4);

    // ---- prologue staging ----
    stage(XT0_OFF);                    // tables all consumed above
    ldraw(xr + cstride);
    __syncthreads();

    f32x4 acc[4];                      // gemm2 accumulators, live across barrier
    const f32x4 z = {0.f, 0.f, 0.f, 0.f};
    int cur = XT0_OFF, nxt = XT1_OFF;

#pragma unroll 1
    for (int bb = 0; bb < 8; ++bb) {
        const int sb = (bb & 1) ? SIN1_OFF : SIN0_OFF;
        // ---- finish previous row: gemm2-SIN + store (after previous barrier) ----
        if (bb > 0) {
            const int sbp = (bb & 1) ? SIN0_OFF : SIN1_OFF;
            float* yr = yb + (size_t)(bb - 1) * cstride;
#pragma unroll
            for (int nt = 0; nt < 4; ++nt) {
                short8 sf = *(const short8*)(smem + sbp + sino[nt]);
                acc[nt] = __builtin_amdgcn_mfma_f32_16x16x32_bf16(pa[2], sf, acc[nt], 0, 0, 0);
            }
#pragma unroll
            for (int nt = 0; nt < 4; ++nt) {
                int m = l15 + 16 * nt;
                float4 v = make_float4(acc[nt][0], acc[nt][1], acc[nt][2], acc[nt][3]);
                *(float4*)(yr + m * 64 + 16 * w + 4 * g) = v;
            }
        }

        // ---- I(bb): fragments, gemm1-dup, gemm2-X, in-register scan, SIN write ----
        short8 xf[4][2];
#pragma unroll
        for (int nt = 0; nt < 4; ++nt)
#pragma unroll
            for (int kt = 0; kt < 2; ++kt)
                xf[nt][kt] = *(const short8*)(smem + cur + xfo[nt][kt]);

        f32x4 sa[4];
#pragma unroll
        for (int nt = 0; nt < 4; ++nt) {
            sa[nt] = __builtin_amdgcn_mfma_f32_16x16x32_bf16(wa[0], xf[nt][0], z, 0, 0, 0);
            sa[nt] = __builtin_amdgcn_mfma_f32_16x16x32_bf16(wa[1], xf[nt][1], sa[nt], 0, 0, 0);
        }
        // gemm2-X (independent of scan; hides MFMA latency)
#pragma unroll
        for (int nt = 0; nt < 4; ++nt)
            acc[nt] = __builtin_amdgcn_mfma_f32_16x16x32_bf16(pa[0], xf[nt][0], z, 0, 0, 0);
        if (w >= 2) {
#pragma unroll
            for (int nt = 0; nt < 4; ++nt)
                acc[nt] = __builtin_amdgcn_mfma_f32_16x16x32_bf16(pa[1], xf[nt][1], acc[nt], 0, 0, 0);
        }

        // in-register scan of this wave's state (s = w&1)
        float pr[4], pi[4];
#pragma unroll
        for (int nt = 0; nt < 4; ++nt) {
            pr[nt] = s ? sa[nt][2] : sa[nt][0];
            pi[nt] = s ? sa[nt][3] : sa[nt][1];
        }
        // local weighted Kogge-Stone within 16-lane rows
#pragma unroll
        for (int nt = 0; nt < 4; ++nt) {
            { float ur = DSHR(pr[nt], 1), ui = DSHR(pi[nt], 1);
              pr[nt] = fmaf(q1r, ur, fmaf(-q1i, ui, pr[nt]));
              pi[nt] = fmaf(q1r, ui, fmaf(q1i, ur, pi[nt])); }
            { float ur = DSHR(pr[nt], 2), ui = DSHR(pi[nt], 2);
              pr[nt] = fmaf(q2r, ur, fmaf(-q2i, ui, pr[nt]));
              pi[nt] = fmaf(q2r, ui, fmaf(q2i, ur, pi[nt])); }
            { float ur = DSHR(pr[nt], 4), ui = DSHR(pi[nt], 4);
              pr[nt] = fmaf(q4r, ur, fmaf(-q4i, ui, pr[nt]));
              pi[nt] = fmaf(q4r, ui, fmaf(q4i, ur, pi[nt])); }
            { float ur = DSHR(pr[nt], 8), ui = DSHR(pi[nt], 8);
              pr[nt] = fmaf(q8r, ur, fmaf(-q8i, ui, pr[nt]));
              pi[nt] = fmaf(q8r, ui, fmaf(q8i, ur, pi[nt])); }
        }
        // serial segment combine: P[nt] += f * bcast15(P[nt-1])
        float bR[3], bI[3];
#pragma unroll
        for (int nt = 1; nt < 4; ++nt) {
            bR[nt - 1] = swz15(pr[nt - 1]);
            bI[nt - 1] = swz15(pi[nt - 1]);
            pr[nt] = fmaf(fr_, bR[nt - 1], fmaf(-fi_, bI[nt - 1], pr[nt]));
            pi[nt] = fmaf(fr_, bI[nt - 1], fmaf(fi_, bR[nt - 1], pi[nt]));
        }
        // exclusive shift + bf16 pack + SIN write (4 disjoint b32 per lane)
#pragma unroll
        for (int nt = 0; nt < 4; ++nt) {
            float eR = DSHR(pr[nt], 1), eI = DSHR(pi[nt], 1);
            float b0R = (nt == 0) ? 0.f : bR[nt - 1];
            float b0I = (nt == 0) ? 0.f : bI[nt - 1];
            eR = (l15 == 0) ? b0R : eR;
            eI = (l15 == 0) ? b0I : eI;
            *(unsigned int*)(smem + sb + sinwb + nt * 1024) = pkrn(eR, eI);
        }

        // next-row staging + prefetch
        if (bb < 7) stage(nxt);
        if (bb < 6) ldraw(xr + (size_t)(bb + 2) * cstride);

        barrier_fast();
        int t = cur; cur = nxt; nxt = t;
    }

    // ---- tail: finish row 7 ----
    {
        const int sbp = SIN1_OFF;      // bb=7 wrote (7&1)=1 -> SIN1
        float* yr = yb + (size_t)7 * cstride;
#pragma unroll
        for (int nt = 0; nt < 4; ++nt) {
            short8 sf = *(const short8*)(smem + sbp + sino[nt]);
            acc[nt] = __builtin_amdgcn_mfma_f32_16x16x32_bf16(pa[2], sf, acc[nt], 0, 0, 0);
        }
#pragma unroll
        for (int nt = 0; nt < 4; ++nt) {
            int m = l15 + 16 * nt;
            float4 v = make_float4(acc[nt][0], acc[nt][1], acc[nt][2], acc[nt][3]);
            *(float4*)(yr + m * 64 + 16 * w + 4 * g) = v;
        }
    }
}

extern "C" void kernel_launch(void* const* d_in, const int* in_sizes, int n_in,
                              void* d_out, int out_size, void* d_ws, size_t ws_size,
                              hipStream_t stream) {
    const float* x      = (const float*)d_in[0];
    const float* A      = (const float*)d_in[1];
    const float* log_dt = (const float*)d_in[4];
    const float* E      = (const float*)d_in[5];
    float* out = (float*)d_out;
    (void)d_ws; (void)ws_size;

    conv_k<<<2 * CH, 256, 0, stream>>>(x, A, log_dt, E, out);
}